// Round 5
// baseline (2068.581 us; speedup 1.0000x reference)
//
#include <hip/hip_runtime.h>
#include <math.h>

#define BB 128
#define T2 2050
#define TT 2049
#define HH 64
#define GG 448   // 7*H
#define KK 100
#define NE 103   // K+3

#define LOG2E 1.44269504088896340736f
#define LN2   0.69314718055994530942f

// gfx9 waitcnt imm: 0xC07F = lgkmcnt(0), vmcnt/expcnt unconstrained
#define WAIT_LGKM0 0xC07Fu

typedef __attribute__((ext_vector_type(2))) _Float16 half2v;

__device__ __forceinline__ float frcp(float x) { return __builtin_amdgcn_rcpf(x); }
__device__ __forceinline__ float sigmoid_fast(float x) {
    return frcp(1.f + exp2f(-x * LOG2E));
}
__device__ __forceinline__ float tanh_fast(float x) {
    float e = exp2f(x * (2.f * LOG2E));
    return 1.f - 2.f * frcp(1.f + e);
}
__device__ __forceinline__ float softplus_fast(float x) {
    float t = exp2f(-fabsf(x) * LOG2E);
    return fmaxf(x, 0.f) + LN2 * log2f(1.f + t);
}
__device__ __forceinline__ float rl(float v, int k) {
    return __int_as_float(__builtin_amdgcn_readlane(__float_as_int(v), k));
}

// pre_emb[e][g] = sum_k in_emb[e][k] * Wx[k][g] + bias[g]   (103 x 448)
__global__ void pre_emb_kernel(const float* __restrict__ in_emb,
                               const float* __restrict__ Wx,
                               const float* __restrict__ bias,
                               float* __restrict__ pre_emb) {
    int e = blockIdx.x;
    int g = threadIdx.x;
    float acc = bias[g];
#pragma unroll
    for (int k = 0; k < HH; ++k)
        acc = fmaf(in_emb[e * HH + k], Wx[k * GG + g], acc);
    pre_emb[e * GG + g] = acc;
}

// One block per batch row; 8 waves (512 threads), 2/SIMD.
// Waves 0-6: gate g = tid; thread holds EXACTLY ONE Wh column (64 VGPRs —
// the R3/R4 two-column design spilled to scratch, which was the regression).
// Wave 7: stores h_t into the output buffer (out[row*100 + 0..63]); the
// logits kernel later expands each row in place.
// State h/c/cb replicated per wave (lane e = element e); h broadcast via
// v_readlane; only the 448 post-nonlinearity gate values cross waves (gbuf,
// double-buffered, ONE raw lgkm-only barrier per step — vmem never drains).
__launch_bounds__(512, 1)
__global__ void scan_kernel(const int* __restrict__ event,
                            const float* __restrict__ dtime,
                            const float* __restrict__ pre_emb,
                            const float* __restrict__ Wh,
                            float* __restrict__ out) {
    const int b    = blockIdx.x;
    const int tid  = threadIdx.x;
    const int w    = tid >> 6;
    const int lane = tid & 63;
    const bool gatew = (w < 7);

    __shared__ float gbuf[2][GG];
    __shared__ int   ev_s[TT];
    __shared__ float dt_s[T2];

    const int*   ev_row = event + b * T2;
    const float* dt_row = dtime + b * T2;
    float*       orow   = out + (size_t)b * TT * KK;

    for (int i = tid; i < TT; i += 512) ev_s[i] = ev_row[i];
    for (int i = tid; i < T2; i += 512) dt_s[i] = dt_row[i];

    float wcol[HH];
    if (gatew) {
#pragma unroll
        for (int k = 0; k < HH; ++k) wcol[k] = Wh[k * GG + tid];
    }

    __syncthreads();

    float h = 0.f, c = 0.f, cb = 0.f;
    float pe = 0.f;
    if (gatew) pe = pre_emb[ev_s[0] * GG + tid];

    for (int t = 0; t < TT; ++t) {
        const int buf = t & 1;
        float pen = 0.f;
        if (gatew) {
            const int tn = (t + 1 < TT) ? (t + 1) : (TT - 1);
            pen = pre_emb[ev_s[tn] * GG + tid];   // 1-ahead prefetch

            float a0 = 0.f, a1 = 0.f, a2 = 0.f, a3 = 0.f;
#pragma unroll
            for (int k4 = 0; k4 < HH / 4; ++k4) {
                const int k = 4 * k4;
                a0 = fmaf(rl(h, k),     wcol[k],     a0);
                a1 = fmaf(rl(h, k + 1), wcol[k + 1], a1);
                a2 = fmaf(rl(h, k + 2), wcol[k + 2], a2);
                a3 = fmaf(rl(h, k + 3), wcol[k + 3], a3);
            }
            const float a = ((a0 + a1) + (a2 + a3)) + pe;

            float v;
            if (w == 2)      v = tanh_fast(a);                   // z
            else if (w == 6) {                                   // delta ->
                const float sp = softplus_fast(a);               // fused decay
                v = exp2f(-sp * dt_s[t + 1] * LOG2E);
            } else           v = sigmoid_fast(a);                // i,f,o,ib,fb
            gbuf[buf][tid] = v;
        }

        __builtin_amdgcn_s_waitcnt(WAIT_LGKM0);
        __builtin_amdgcn_s_barrier();

        const float gi  = gbuf[buf][lane];
        const float gf  = gbuf[buf][64 + lane];
        const float gz  = gbuf[buf][128 + lane];
        const float go  = gbuf[buf][192 + lane];
        const float gib = gbuf[buf][256 + lane];
        const float gfb = gbuf[buf][320 + lane];
        const float dec = gbuf[buf][384 + lane];
        const float ci  = fmaf(gf, c, gi * gz);
        const float cbi = fmaf(gfb, cb, gib * gz);
        const float cn  = fmaf(ci - cbi, dec, cbi);
        h  = go * tanh_fast(cn);
        c  = cn;
        cb = cbi;
        pe = pen;

        if (w == 7) orow[(size_t)t * KK + lane] = h;  // fire-and-forget
    }
}

// In-place logits: each wave owns whole rows. Reads h from out[row][0..63],
// computes all 100 intensities (f16 dot2: both col-halves fit in 64 VGPRs),
// overwrites the row. Same-wave load-before-store => race-free in place.
__launch_bounds__(256, 2)
__global__ void logits_kernel(const float* __restrict__ out_emb,
                              float* __restrict__ out) {
    const int lane = threadIdx.x & 63;
    const int gw   = blockIdx.x * 4 + (threadIdx.x >> 6);   // 0..4095
    const int NR   = BB * TT;
    const int STEP = 4096;

    half2v w1[HH / 2], w2[HH / 2];
#pragma unroll
    for (int j = 0; j < HH / 2; ++j) {
        w1[j] = half2v{(_Float16)out_emb[lane * HH + 2 * j],
                       (_Float16)out_emb[lane * HH + 2 * j + 1]};
        if (lane < KK - HH)   // cols 64..99
            w2[j] = half2v{(_Float16)out_emb[(HH + lane) * HH + 2 * j],
                           (_Float16)out_emb[(HH + lane) * HH + 2 * j + 1]};
        else
            w2[j] = half2v{(_Float16)0.f, (_Float16)0.f};
    }

    int   r  = gw;
    float hv = out[(size_t)r * KK + lane];
    for (;;) {
        const int rn = r + STEP;
        float hn = 0.f;
        if (rn < NR) hn = out[(size_t)rn * KK + lane];   // prefetch

        // pack (h[2j], h[2j+1]) on even lanes via xor-1 swizzle
        const float hp = __int_as_float(
            __builtin_amdgcn_ds_swizzle(__float_as_int(hv), 0x041F));
        const half2v pk = half2v{(_Float16)hv, (_Float16)hp};
        const int pkb = __builtin_bit_cast(int, pk);

        float a1 = 0.f, a2 = 0.f;
#pragma unroll
        for (int j = 0; j < HH / 2; ++j) {
            const half2v s = __builtin_bit_cast(
                half2v, __builtin_amdgcn_readlane(pkb, 2 * j));
            a1 = __builtin_amdgcn_fdot2(s, w1[j], a1, false);
            a2 = __builtin_amdgcn_fdot2(s, w2[j], a2, false);
        }
        out[(size_t)r * KK + lane] = softplus_fast(a1);
        if (lane < KK - HH)
            out[(size_t)r * KK + HH + lane] = softplus_fast(a2);

        if (rn >= NR) break;
        hv = hn;
        r  = rn;
    }
}

extern "C" void kernel_launch(void* const* d_in, const int* in_sizes, int n_in,
                              void* d_out, int out_size, void* d_ws, size_t ws_size,
                              hipStream_t stream) {
    const int*   event  = (const int*)d_in[0];
    const float* dtime  = (const float*)d_in[1];
    const float* in_emb = (const float*)d_in[2];
    const float* Wx     = (const float*)d_in[3];
    const float* Wh     = (const float*)d_in[4];
    const float* bias   = (const float*)d_in[5];
    const float* oe     = (const float*)d_in[6];
    float*       out    = (float*)d_out;

    float* pre_emb = (float*)d_ws;  // 103*448*4 = 184,576 bytes

    pre_emb_kernel<<<NE, GG, 0, stream>>>(in_emb, Wx, bias, pre_emb);
    scan_kernel<<<BB, 512, 0, stream>>>(event, dtime, pre_emb, Wh, out);
    logits_kernel<<<1024, 256, 0, stream>>>(oe, out);
}